// Round 14
// baseline (1362.638 us; speedup 1.0000x reference)
//
#include <hip/hip_runtime.h>
#include <hip/hip_fp16.h>
#include <math.h>

// Problem constants
#define KDIM  2048
// d_out layout (floats): y | k | v
#define Y_OFF 0
#define K_OFF 8388608
#define V_OFF 16777216

typedef _Float16 half2v __attribute__((ext_vector_type(2)));

__device__ __forceinline__ float fdot2f(half2v a, half2v b, float c) {
#if __has_builtin(__builtin_amdgcn_fdot2)
    return __builtin_amdgcn_fdot2(a, b, c, false);
#else
    return fmaf((float)a[1], (float)b[1], fmaf((float)a[0], (float)b[0], c));
#endif
}

// ---------------------------------------------------------------------------
// Kernel 1 (merged):
//  bid < 256 : qk path, fp32, 8x16 thread tile, BM=128 BN=256 BK=32.
//              21.3 FMA per ds_read_b128 -> VALU-bound (was 16:1 LDS-bound).
//  bid >= 256: v path, fp16-pair dot2 (unchanged from R13).
// LDS union: As[32][132] + Bs[32][260] = 50.2 KB (v path uses a prefix).
// No launch-bounds min-occupancy, no reg-prefetch (R6/R7 lessons).
// ---------------------------------------------------------------------------
__global__ __launch_bounds__(256) void gemm_merged_kernel(
    const float* __restrict__ x, const float* __restrict__ Wc,
    const float* __restrict__ bc, const float* __restrict__ fq,
    float* __restrict__ qws, float* __restrict__ out)
{
    __shared__ __align__(16) float LDS[32 * 132 + 32 * 260];   // 50.2 KB

    const int t   = threadIdx.x;
    const int bid = blockIdx.x;

    if (bid < 256) {
        // ================= qk path (fp32, argmax-critical), 8x16 ==========
        float (*As)[132] = (float(*)[132])LDS;
        float (*Bs)[260] = (float(*)[260])(LDS + 32 * 132);

        const int bx = bid & 7;      // 0..7  -> 256-col tiles (cols 0..2047)
        const int by = bid >> 3;     // 0..31 -> 128-row tiles
        const int tx = t & 15, ty = t >> 4;

        // A staging: row = t&127, k-half = (t>>7)*16 (4 float4)
        const int sa_row = t & 127;
        const int sa_k   = (t >> 7) << 4;
        const int arow   = by * 128 + sa_row;
        // B staging: row = t (0..255), all 32 k (8 float4)
        int bsrc;
        {
            const int c = bx * 256 + t;
            if (c < 1024) bsrc = ((c >> 6) << 7) + (c & 63);
            else          bsrc = 2048 + (((c - 1024) >> 6) << 7) + (c & 63);
        }

        float acc[8][16];
        #pragma unroll
        for (int i = 0; i < 8; ++i)
            #pragma unroll
            for (int j = 0; j < 16; ++j) acc[i][j] = 0.f;

        for (int kt = 0; kt < 64; ++kt) {
            const int k0 = kt << 5;

            // ---- stage A (k-major transpose)
            #pragma unroll
            for (int i = 0; i < 4; ++i) {
                float4 va = *(const float4*)(x + (size_t)arow * KDIM + k0 + sa_k + (i << 2));
                const float* pa = (const float*)&va;
                #pragma unroll
                for (int e = 0; e < 4; ++e)
                    As[sa_k + (i << 2) + e][sa_row] = pa[e];
            }
            // ---- stage B (k-major transpose)
            #pragma unroll
            for (int i = 0; i < 8; ++i) {
                float4 vb = *(const float4*)(Wc + (size_t)bsrc * KDIM + k0 + (i << 2));
                const float* pb = (const float*)&vb;
                #pragma unroll
                for (int e = 0; e < 4; ++e)
                    Bs[(i << 2) + e][t] = pb[e];
            }
            __syncthreads();

            // ---- compute 32 kk, 8x16 per thread
            #pragma unroll
            for (int kk = 0; kk < 32; ++kk) {
                float4 a0 = *(const float4*)(&As[kk][ty << 3]);
                float4 a1 = *(const float4*)(&As[kk][(ty << 3) + 4]);
                float4 b0 = *(const float4*)(&Bs[kk][tx << 2]);
                float4 b1 = *(const float4*)(&Bs[kk][64 + (tx << 2)]);
                float4 b2 = *(const float4*)(&Bs[kk][128 + (tx << 2)]);
                float4 b3 = *(const float4*)(&Bs[kk][192 + (tx << 2)]);
                const float av[8]  = {a0.x, a0.y, a0.z, a0.w, a1.x, a1.y, a1.z, a1.w};
                const float bv[16] = {b0.x, b0.y, b0.z, b0.w, b1.x, b1.y, b1.z, b1.w,
                                      b2.x, b2.y, b2.z, b2.w, b3.x, b3.y, b3.z, b3.w};
                #pragma unroll
                for (int i = 0; i < 8; ++i)
                    #pragma unroll
                    for (int j = 0; j < 16; ++j)
                        acc[i][j] = fmaf(av[i], bv[j], acc[i][j]);
            }
            __syncthreads();
        }

        // ---- epilogue: bias + rope-scale + scatter (q compact*2, k dup)
        float* kout = out + K_OFF;
        #pragma unroll
        for (int i = 0; i < 8; ++i) {
            const int r = by * 128 + (ty << 3) + i;
            const int b = r >> 11, s = r & 2047;
            #pragma unroll
            for (int g = 0; g < 4; ++g) {
                #pragma unroll
                for (int j = 0; j < 4; ++j) {
                    const int c = bx * 256 + (g << 6) + (tx << 2) + j;
                    const float a = acc[i][(g << 2) + j];
                    const int sec = c >> 10;          // 0=q, 1=k
                    const int cc  = c & 1023;
                    const int h = cc >> 6, d2 = cc & 63;
                    const float val = (a + bc[sec * 2048 + h * 128 + d2]) * fq[s * 64 + d2];
                    if (sec == 0) {
                        qws[((size_t)(b * 16 + h) * 2048 + s) * 64 + d2] = 2.0f * val;
                    } else {
                        const size_t o = ((size_t)(b * 16 + h) * 2048 + s) * 128 + d2;
                        kout[o] = val; kout[o + 64] = val;
                    }
                }
            }
        }
    } else {
        // ================= v path (fp16-pair dot2, fp32 accum) =============
        half2v (*As2)[132] = (half2v(*)[132])LDS;
        half2v (*Bs2)[132] = (half2v(*)[132])(LDS + 16 * 132);

        const int sub = bid - 256;            // 0..511
        const int bx = sub & 15;              // v col tile
        const int by = sub >> 4;              // row tile
        const int tx = t & 15, ty = t >> 4;

        const int srow = t >> 1;              // 0..127
        const int kseg = (t & 1) << 4;        // 0 or 16
        const int kp0  = (t & 1) << 3;        // pair base 0 or 8

        const int arow = by * 128 + srow;
        const int vsrc = 4096 + bx * 128 + srow;

        float acc[8][8];
        #pragma unroll
        for (int i = 0; i < 8; ++i)
            #pragma unroll
            for (int j = 0; j < 8; ++j) acc[i][j] = 0.f;

        for (int kt = 0; kt < 64; ++kt) {
            const int k0 = kt << 5;
            float4 va[4], vb[4];
            #pragma unroll
            for (int i = 0; i < 4; ++i) {
                va[i] = *(const float4*)(x  + (size_t)arow * KDIM + k0 + kseg + (i << 2));
                vb[i] = *(const float4*)(Wc + (size_t)vsrc * KDIM + k0 + kseg + (i << 2));
            }
            #pragma unroll
            for (int i = 0; i < 4; ++i) {
                const float* pa = (const float*)&va[i];
                const float* pb = (const float*)&vb[i];
                #pragma unroll
                for (int e = 0; e < 2; ++e) {
                    half2v ha; ha[0] = (_Float16)pa[2 * e]; ha[1] = (_Float16)pa[2 * e + 1];
                    half2v hb; hb[0] = (_Float16)pb[2 * e]; hb[1] = (_Float16)pb[2 * e + 1];
                    As2[kp0 + (i << 1) + e][srow] = ha;
                    Bs2[kp0 + (i << 1) + e][srow] = hb;
                }
            }
            __syncthreads();

            #pragma unroll
            for (int kp = 0; kp < 16; ++kp) {
                uint4 au0 = *reinterpret_cast<const uint4*>(&As2[kp][ty << 3]);
                uint4 au1 = *reinterpret_cast<const uint4*>(&As2[kp][(ty << 3) + 4]);
                const half2v* a2lo = reinterpret_cast<const half2v*>(&au0);
                const half2v* a2hi = reinterpret_cast<const half2v*>(&au1);
                uint4 bu0 = *reinterpret_cast<const uint4*>(&Bs2[kp][tx << 2]);
                uint4 bu1 = *reinterpret_cast<const uint4*>(&Bs2[kp][64 + (tx << 2)]);
                const half2v* b0 = reinterpret_cast<const half2v*>(&bu0);
                const half2v* b1 = reinterpret_cast<const half2v*>(&bu1);
                #pragma unroll
                for (int i = 0; i < 8; ++i) {
                    const half2v ai = (i < 4) ? a2lo[i] : a2hi[i - 4];
                    #pragma unroll
                    for (int j = 0; j < 4; ++j) {
                        acc[i][j]     = fdot2f(ai, b0[j], acc[i][j]);
                        acc[i][4 + j] = fdot2f(ai, b1[j], acc[i][4 + j]);
                    }
                }
            }
            __syncthreads();
        }

        float* vout = out + V_OFF;
        #pragma unroll
        for (int i = 0; i < 8; ++i) {
            const int r = by * 128 + (ty << 3) + i;
            const int b = r >> 11, s = r & 2047;
            #pragma unroll
            for (int g = 0; g < 2; ++g) {
                #pragma unroll
                for (int j = 0; j < 4; ++j) {
                    const int cc = bx * 128 + (g << 6) + (tx << 2) + j;
                    const int h = cc >> 7, d = cc & 127;
                    vout[((size_t)(b * 16 + h) * 2048 + s) * 128 + d] =
                        acc[i][(g << 2) + j] + bc[4096 + cc];
                }
            }
        }
    }
}

// ---------------------------------------------------------------------------
// Kernel 2: register-tiled flash attention, PV via v_dot2_f32_f16
// (unchanged from R13).
// ---------------------------------------------------------------------------
__global__ __launch_bounds__(256, 2) void attn_kernel(
    const float* __restrict__ qws, const float* __restrict__ kbuf,
    const float* __restrict__ vbuf, float* __restrict__ y)
{
    __shared__ __align__(16) float  Qt[64][128];
    __shared__ __align__(16) float  Kt[64][64];
    __shared__ __align__(16) __half Vt[128][64];
    __shared__ __align__(16) __half Ps[4][32][64];

    const int t   = threadIdx.x;
    const int bid = blockIdx.x;
    const int bh  = bid & 31;
    const int qb  = bid >> 5;
    const int tr  = t >> 4;
    const int tc  = t & 15;
    const int s0  = qb << 7;
    const int wid = t >> 6;
    const int ltr = tr & 3;

    const float* qp = qws  + (size_t)bh * (2048 * 64);
    const float* kb = kbuf + (size_t)bh * (2048 * 128);
    const float* vb = vbuf + (size_t)bh * (2048 * 128);

    const int kk0 = t >> 2, sg = t & 3;
    const int kp  = t >> 3;
    const int ds0 = (t & 7) << 4;

    {
        const int qr = t & 127;
        const int dh = (t >> 7) << 5;
        const float* src = qp + (size_t)(s0 + qr) * 64 + dh;
        #pragma unroll
        for (int i = 0; i < 8; ++i) {
            float4 v4 = *(const float4*)(src + (i << 2));
            Qt[dh + (i << 2) + 0][qr] = v4.x;
            Qt[dh + (i << 2) + 1][qr] = v4.y;
            Qt[dh + (i << 2) + 2][qr] = v4.z;
            Qt[dh + (i << 2) + 3][qr] = v4.w;
        }
    }
    {
        #pragma unroll
        for (int i = 0; i < 4; ++i) {
            float4 k4 = *(const float4*)(kb + (size_t)kk0 * 128 + sg * 16 + (i << 2));
            Kt[sg * 16 + (i << 2) + 0][kk0] = k4.x;
            Kt[sg * 16 + (i << 2) + 1][kk0] = k4.y;
            Kt[sg * 16 + (i << 2) + 2][kk0] = k4.z;
            Kt[sg * 16 + (i << 2) + 3][kk0] = k4.w;
        }
        #pragma unroll
        for (int u = 0; u < 4; ++u) {
            float4 v0 = *(const float4*)(vb + (size_t)(2 * kp) * 128 + ds0 + (u << 2));
            float4 v1 = *(const float4*)(vb + (size_t)(2 * kp + 1) * 128 + ds0 + (u << 2));
            const float* p0 = (const float*)&v0;
            const float* p1 = (const float*)&v1;
            #pragma unroll
            for (int e = 0; e < 4; ++e) {
                const int d = ds0 + (u << 2) + e;
                const int off = (2 * kp) ^ (((d >> 2) & 7) << 3);
                half2v h; h[0] = (_Float16)p0[e]; h[1] = (_Float16)p1[e];
                *reinterpret_cast<half2v*>(&Vt[d][off]) = h;
            }
        }
    }
    __syncthreads();

    float accO[8][8];
    #pragma unroll
    for (int i = 0; i < 8; ++i)
        #pragma unroll
        for (int j = 0; j < 8; ++j) accO[i][j] = 0.f;
    float mrow[8], lrow[8];
    #pragma unroll
    for (int i = 0; i < 8; ++i) { mrow[i] = -INFINITY; lrow[i] = 0.f; }

    const float scale = 0.08838834764831845f;  // 1/sqrt(128)
    const int   pvs   = (tc & 7) << 3;
    const int   pss   = ltr << 3;

    for (int kt = 0; kt < 32; ++kt) {
        float4 kreg[4], vr0[4], vr1[4];
        if (kt < 31) {
            const size_t base = (size_t)(kt + 1) * 64 * 128;
            #pragma unroll
            for (int i = 0; i < 4; ++i)
                kreg[i] = *(const float4*)(kb + base + (size_t)kk0 * 128 + sg * 16 + (i << 2));
            #pragma unroll
            for (int u = 0; u < 4; ++u) {
                vr0[u] = *(const float4*)(vb + base + (size_t)(2 * kp) * 128 + ds0 + (u << 2));
                vr1[u] = *(const float4*)(vb + base + (size_t)(2 * kp + 1) * 128 + ds0 + (u << 2));
            }
        }

        float sv[8][4];
        #pragma unroll
        for (int i = 0; i < 8; ++i)
            #pragma unroll
            for (int j = 0; j < 4; ++j) sv[i][j] = 0.f;

        #pragma unroll 4
        for (int d = 0; d < 64; ++d) {
            float4 a0 = *(const float4*)(&Qt[d][tr << 3]);
            float4 a1 = *(const float4*)(&Qt[d][(tr << 3) + 4]);
            float4 kv = *(const float4*)(&Kt[d][tc << 2]);
            const float av[8] = {a0.x, a0.y, a0.z, a0.w, a1.x, a1.y, a1.z, a1.w};
            const float bv[4] = {kv.x, kv.y, kv.z, kv.w};
            #pragma unroll
            for (int i = 0; i < 8; ++i)
                #pragma unroll
                for (int j = 0; j < 4; ++j)
                    sv[i][j] = fmaf(av[i], bv[j], sv[i][j]);
        }

        #pragma unroll
        for (int i = 0; i < 8; ++i) {
            #pragma unroll
            for (int j = 0; j < 4; ++j) sv[i][j] *= scale;
            float mx = fmaxf(fmaxf(sv[i][0], sv[i][1]), fmaxf(sv[i][2], sv[i][3]));
            mx = fmaxf(mx, __shfl_xor(mx, 1));
            mx = fmaxf(mx, __shfl_xor(mx, 2));
            mx = fmaxf(mx, __shfl_xor(mx, 4));
            mx = fmaxf(mx, __shfl_xor(mx, 8));
            if (mx > mrow[i]) {
                const float al = __expf(mrow[i] - mx);
                mrow[i] = mx;
                lrow[i] *= al;
                #pragma unroll
                for (int j = 0; j < 8; ++j) accO[i][j] *= al;
            }
            float ps = 0.f;
            #pragma unroll
            for (int j = 0; j < 4; ++j) {
                const float p = __expf(sv[i][j] - mrow[i]);
                sv[i][j] = p;
                ps += p;
            }
            ps += __shfl_xor(ps, 1);
            ps += __shfl_xor(ps, 2);
            ps += __shfl_xor(ps, 4);
            ps += __shfl_xor(ps, 8);
            lrow[i] += ps;
        }

        #pragma unroll
        for (int i = 0; i < 8; ++i) {
            half2v h0; h0[0] = (_Float16)sv[i][0]; h0[1] = (_Float16)sv[i][1];
            half2v h1; h1[0] = (_Float16)sv[i][2]; h1[1] = (_Float16)sv[i][3];
            uint2 wv;
            wv.x = __builtin_bit_cast(unsigned int, h0);
            wv.y = __builtin_bit_cast(unsigned int, h1);
            *reinterpret_cast<uint2*>(&Ps[wid][(ltr << 3) + i][(tc << 2) ^ pss]) = wv;
        }
        asm volatile("s_waitcnt lgkmcnt(0)" ::: "memory");

        for (int c = 0; c < 8; ++c) {
            uint4 vvu[8];
            #pragma unroll
            for (int e = 0; e < 8; ++e) {
                const int d = (e < 4) ? (tc << 2) + e : 64 + (tc << 2) + (e - 4);
                vvu[e] = *reinterpret_cast<const uint4*>(&Vt[d][(c << 3) ^ pvs]);
            }
            #pragma unroll
            for (int i = 0; i < 8; ++i) {
                uint4 ppu = *reinterpret_cast<const uint4*>(
                    &Ps[wid][(ltr << 3) + i][(c << 3) ^ pss]);
                const half2v* ph = reinterpret_cast<const half2v*>(&ppu);
                #pragma unroll
                for (int e = 0; e < 8; ++e) {
                    const half2v* vh = reinterpret_cast<const half2v*>(&vvu[e]);
                    float a = accO[i][e];
                    a = fdot2f(ph[0], vh[0], a);
                    a = fdot2f(ph[1], vh[1], a);
                    a = fdot2f(ph[2], vh[2], a);
                    a = fdot2f(ph[3], vh[3], a);
                    accO[i][e] = a;
                }
            }
        }

        if (kt < 31) {
            __syncthreads();
            #pragma unroll
            for (int i = 0; i < 4; ++i) {
                Kt[sg * 16 + (i << 2) + 0][kk0] = kreg[i].x;
                Kt[sg * 16 + (i << 2) + 1][kk0] = kreg[i].y;
                Kt[sg * 16 + (i << 2) + 2][kk0] = kreg[i].z;
                Kt[sg * 16 + (i << 2) + 3][kk0] = kreg[i].w;
            }
            #pragma unroll
            for (int u = 0; u < 4; ++u) {
                const float* p0 = (const float*)&vr0[u];
                const float* p1 = (const float*)&vr1[u];
                #pragma unroll
                for (int e = 0; e < 4; ++e) {
                    const int d = ds0 + (u << 2) + e;
                    const int off = (2 * kp) ^ (((d >> 2) & 7) << 3);
                    half2v h; h[0] = (_Float16)p0[e]; h[1] = (_Float16)p1[e];
                    *reinterpret_cast<half2v*>(&Vt[d][off]) = h;
                }
            }
            __syncthreads();
        }
    }

    const int b = bh >> 4, h = bh & 15;
    #pragma unroll
    for (int i = 0; i < 8; ++i) {
        const float inv = 1.f / lrow[i];
        const int srow = s0 + (tr << 3) + i;
        float* yp = y + ((size_t)(b * 2048 + srow)) * 2048 + h * 128;
        float4 o0, o1;
        o0.x = accO[i][0] * inv; o0.y = accO[i][1] * inv;
        o0.z = accO[i][2] * inv; o0.w = accO[i][3] * inv;
        o1.x = accO[i][4] * inv; o1.y = accO[i][5] * inv;
        o1.z = accO[i][6] * inv; o1.w = accO[i][7] * inv;
        *(float4*)(yp + (tc << 2))      = o0;
        *(float4*)(yp + 64 + (tc << 2)) = o1;
    }
}

extern "C" void kernel_launch(void* const* d_in, const int* in_sizes, int n_in,
                              void* d_out, int out_size, void* d_ws, size_t ws_size,
                              hipStream_t stream)
{
    const float* x  = (const float*)d_in[0];
    const float* Wc = (const float*)d_in[1];
    const float* bc = (const float*)d_in[2];
    const float* fq = (const float*)d_in[3];
    float* out = (float*)d_out;
    float* qws = (float*)d_ws;   // compact q, (B,H,S,64) fp32 = 16 MiB

    gemm_merged_kernel<<<768, 256, 0, stream>>>(x, Wc, bc, fq, qws, out);
    attn_kernel<<<512, 256, 0, stream>>>(qws, out + K_OFF, out + V_OFF, out + Y_OFF);
}

// Round 15
// 1216.533 us; speedup vs baseline: 1.1201x; 1.1201x over previous
//
#include <hip/hip_runtime.h>
#include <hip/hip_fp16.h>
#include <math.h>

// Problem constants
#define KDIM  2048
// d_out layout (floats): y | k | v
#define Y_OFF 0
#define K_OFF 8388608
#define V_OFF 16777216

typedef _Float16 half2v __attribute__((ext_vector_type(2)));

__device__ __forceinline__ float fdot2f(half2v a, half2v b, float c) {
#if __has_builtin(__builtin_amdgcn_fdot2)
    return __builtin_amdgcn_fdot2(a, b, c, false);
#else
    return fmaf((float)a[1], (float)b[1], fmaf((float)a[0], (float)b[0], c));
#endif
}

// ---------------------------------------------------------------------------
// Kernel 1 (merged, R13 configuration — best measured): even blocks run the
// fp32 qk path (8x8 tile, LDS-lean, 4 blocks/CU), odd blocks run the
// fp16-dot2 v path (VALU-bound). Co-residency overlaps their stalls.
// R14's 8x16 variant regressed (VGPR 136 -> 1 block/CU, latency-exposed).
// ---------------------------------------------------------------------------
__global__ __launch_bounds__(256) void gemm_merged_kernel(
    const float* __restrict__ x, const float* __restrict__ Wc,
    const float* __restrict__ bc, const float* __restrict__ fq,
    float* __restrict__ qws, float* __restrict__ out)
{
    __shared__ __align__(16) float LDS[2 * 32 * 132];   // 33.8 KB union

    const int t   = threadIdx.x;
    const int bid = blockIdx.x;           // 0..1023
    const int which = bid & 1;            // 0 = qk, 1 = v
    const int sub = bid >> 1;             // 0..511
    const int bx = sub & 15;              // col tile
    const int by = sub >> 4;              // row tile 0..31
    const int tx = t & 15, ty = t >> 4;

    const int srow = t >> 1;              // 0..127
    const int kseg = (t & 1) << 4;        // 0 or 16

    const int arow = by * 128 + srow;

    float acc[8][8];
    #pragma unroll
    for (int i = 0; i < 8; ++i)
        #pragma unroll
        for (int j = 0; j < 8; ++j) acc[i][j] = 0.f;

    if (which == 0) {
        // ================= qk path (fp32, argmax-critical) =================
        float (*As)[132] = (float(*)[132])LDS;
        float (*Bs)[132] = (float(*)[132])(LDS + 32 * 132);

        int bsrc;
        {
            const int c = bx * 128 + srow;
            if (c < 1024) bsrc = ((c >> 6) << 7) + (c & 63);
            else          bsrc = 2048 + (((c - 1024) >> 6) << 7) + (c & 63);
        }

        for (int kt = 0; kt < 64; ++kt) {
            const int k0 = kt << 5;
            float4 va[4], vb[4];
            #pragma unroll
            for (int i = 0; i < 4; ++i) {
                va[i] = *(const float4*)(x  + (size_t)arow * KDIM + k0 + kseg + (i << 2));
                vb[i] = *(const float4*)(Wc + (size_t)bsrc * KDIM + k0 + kseg + (i << 2));
            }
            #pragma unroll
            for (int i = 0; i < 4; ++i) {
                const float* pa = (const float*)&va[i];
                const float* pb = (const float*)&vb[i];
                #pragma unroll
                for (int e = 0; e < 4; ++e) {
                    As[kseg + (i << 2) + e][srow] = pa[e];
                    Bs[kseg + (i << 2) + e][srow] = pb[e];
                }
            }
            __syncthreads();

            #pragma unroll
            for (int kk = 0; kk < 32; ++kk) {
                float4 a0 = *(const float4*)(&As[kk][ty << 3]);
                float4 a1 = *(const float4*)(&As[kk][(ty << 3) + 4]);
                float4 b0 = *(const float4*)(&Bs[kk][tx << 2]);
                float4 b1 = *(const float4*)(&Bs[kk][64 + (tx << 2)]);
                const float av[8] = {a0.x, a0.y, a0.z, a0.w, a1.x, a1.y, a1.z, a1.w};
                const float bv[8] = {b0.x, b0.y, b0.z, b0.w, b1.x, b1.y, b1.z, b1.w};
                #pragma unroll
                for (int i = 0; i < 8; ++i)
                    #pragma unroll
                    for (int j = 0; j < 8; ++j)
                        acc[i][j] = fmaf(av[i], bv[j], acc[i][j]);
            }
            __syncthreads();
        }

        float* kout = out + K_OFF;
        #pragma unroll
        for (int i = 0; i < 8; ++i) {
            const int r = by * 128 + (ty << 3) + i;
            const int b = r >> 11, s = r & 2047;
            #pragma unroll
            for (int g = 0; g < 2; ++g) {
                #pragma unroll
                for (int j = 0; j < 4; ++j) {
                    const int c = bx * 128 + (g << 6) + (tx << 2) + j;
                    const float a = acc[i][(g << 2) + j];
                    const int sec = c >> 10;          // 0=q, 1=k
                    const int cc  = c & 1023;
                    const int h = cc >> 6, d2 = cc & 63;
                    const float val = (a + bc[sec * 2048 + h * 128 + d2]) * fq[s * 64 + d2];
                    if (sec == 0) {
                        qws[((size_t)(b * 16 + h) * 2048 + s) * 64 + d2] = 2.0f * val;
                    } else {
                        const size_t o = ((size_t)(b * 16 + h) * 2048 + s) * 128 + d2;
                        kout[o] = val; kout[o + 64] = val;
                    }
                }
            }
        }
    } else {
        // ================= v path (fp16-pair dot2, fp32 accum) =============
        half2v (*As2)[132] = (half2v(*)[132])LDS;
        half2v (*Bs2)[132] = (half2v(*)[132])(LDS + 16 * 132);  // float units

        const int kp0  = (t & 1) << 3;        // pair base 0 or 8
        const int vsrc = 4096 + bx * 128 + srow;

        for (int kt = 0; kt < 64; ++kt) {
            const int k0 = kt << 5;
            float4 va[4], vb[4];
            #pragma unroll
            for (int i = 0; i < 4; ++i) {
                va[i] = *(const float4*)(x  + (size_t)arow * KDIM + k0 + kseg + (i << 2));
                vb[i] = *(const float4*)(Wc + (size_t)vsrc * KDIM + k0 + kseg + (i << 2));
            }
            #pragma unroll
            for (int i = 0; i < 4; ++i) {
                const float* pa = (const float*)&va[i];
                const float* pb = (const float*)&vb[i];
                #pragma unroll
                for (int e = 0; e < 2; ++e) {
                    half2v ha; ha[0] = (_Float16)pa[2 * e]; ha[1] = (_Float16)pa[2 * e + 1];
                    half2v hb; hb[0] = (_Float16)pb[2 * e]; hb[1] = (_Float16)pb[2 * e + 1];
                    As2[kp0 + (i << 1) + e][srow] = ha;
                    Bs2[kp0 + (i << 1) + e][srow] = hb;
                }
            }
            __syncthreads();

            #pragma unroll
            for (int kp = 0; kp < 16; ++kp) {
                uint4 au0 = *reinterpret_cast<const uint4*>(&As2[kp][ty << 3]);
                uint4 au1 = *reinterpret_cast<const uint4*>(&As2[kp][(ty << 3) + 4]);
                const half2v* a2lo = reinterpret_cast<const half2v*>(&au0);
                const half2v* a2hi = reinterpret_cast<const half2v*>(&au1);
                uint4 bu0 = *reinterpret_cast<const uint4*>(&Bs2[kp][tx << 2]);
                uint4 bu1 = *reinterpret_cast<const uint4*>(&Bs2[kp][64 + (tx << 2)]);
                const half2v* b0 = reinterpret_cast<const half2v*>(&bu0);
                const half2v* b1 = reinterpret_cast<const half2v*>(&bu1);
                #pragma unroll
                for (int i = 0; i < 8; ++i) {
                    const half2v ai = (i < 4) ? a2lo[i] : a2hi[i - 4];
                    #pragma unroll
                    for (int j = 0; j < 4; ++j) {
                        acc[i][j]     = fdot2f(ai, b0[j], acc[i][j]);
                        acc[i][4 + j] = fdot2f(ai, b1[j], acc[i][4 + j]);
                    }
                }
            }
            __syncthreads();
        }

        float* vout = out + V_OFF;
        #pragma unroll
        for (int i = 0; i < 8; ++i) {
            const int r = by * 128 + (ty << 3) + i;
            const int b = r >> 11, s = r & 2047;
            #pragma unroll
            for (int g = 0; g < 2; ++g) {
                #pragma unroll
                for (int j = 0; j < 4; ++j) {
                    const int cc = bx * 128 + (g << 6) + (tx << 2) + j;
                    const int h = cc >> 7, d = cc & 127;
                    vout[((size_t)(b * 16 + h) * 2048 + s) * 128 + d] =
                        acc[i][(g << 2) + j] + bc[4096 + cc];
                }
            }
        }
    }
}

// ---------------------------------------------------------------------------
// Kernel 2: register-tiled flash attention, PV via v_dot2_f32_f16
// (unchanged).
// ---------------------------------------------------------------------------
__global__ __launch_bounds__(256, 2) void attn_kernel(
    const float* __restrict__ qws, const float* __restrict__ kbuf,
    const float* __restrict__ vbuf, float* __restrict__ y)
{
    __shared__ __align__(16) float  Qt[64][128];
    __shared__ __align__(16) float  Kt[64][64];
    __shared__ __align__(16) __half Vt[128][64];
    __shared__ __align__(16) __half Ps[4][32][64];

    const int t   = threadIdx.x;
    const int bid = blockIdx.x;
    const int bh  = bid & 31;
    const int qb  = bid >> 5;
    const int tr  = t >> 4;
    const int tc  = t & 15;
    const int s0  = qb << 7;
    const int wid = t >> 6;
    const int ltr = tr & 3;

    const float* qp = qws  + (size_t)bh * (2048 * 64);
    const float* kb = kbuf + (size_t)bh * (2048 * 128);
    const float* vb = vbuf + (size_t)bh * (2048 * 128);

    const int kk0 = t >> 2, sg = t & 3;
    const int kp  = t >> 3;
    const int ds0 = (t & 7) << 4;

    {
        const int qr = t & 127;
        const int dh = (t >> 7) << 5;
        const float* src = qp + (size_t)(s0 + qr) * 64 + dh;
        #pragma unroll
        for (int i = 0; i < 8; ++i) {
            float4 v4 = *(const float4*)(src + (i << 2));
            Qt[dh + (i << 2) + 0][qr] = v4.x;
            Qt[dh + (i << 2) + 1][qr] = v4.y;
            Qt[dh + (i << 2) + 2][qr] = v4.z;
            Qt[dh + (i << 2) + 3][qr] = v4.w;
        }
    }
    {
        #pragma unroll
        for (int i = 0; i < 4; ++i) {
            float4 k4 = *(const float4*)(kb + (size_t)kk0 * 128 + sg * 16 + (i << 2));
            Kt[sg * 16 + (i << 2) + 0][kk0] = k4.x;
            Kt[sg * 16 + (i << 2) + 1][kk0] = k4.y;
            Kt[sg * 16 + (i << 2) + 2][kk0] = k4.z;
            Kt[sg * 16 + (i << 2) + 3][kk0] = k4.w;
        }
        #pragma unroll
        for (int u = 0; u < 4; ++u) {
            float4 v0 = *(const float4*)(vb + (size_t)(2 * kp) * 128 + ds0 + (u << 2));
            float4 v1 = *(const float4*)(vb + (size_t)(2 * kp + 1) * 128 + ds0 + (u << 2));
            const float* p0 = (const float*)&v0;
            const float* p1 = (const float*)&v1;
            #pragma unroll
            for (int e = 0; e < 4; ++e) {
                const int d = ds0 + (u << 2) + e;
                const int off = (2 * kp) ^ (((d >> 2) & 7) << 3);
                half2v h; h[0] = (_Float16)p0[e]; h[1] = (_Float16)p1[e];
                *reinterpret_cast<half2v*>(&Vt[d][off]) = h;
            }
        }
    }
    __syncthreads();

    float accO[8][8];
    #pragma unroll
    for (int i = 0; i < 8; ++i)
        #pragma unroll
        for (int j = 0; j < 8; ++j) accO[i][j] = 0.f;
    float mrow[8], lrow[8];
    #pragma unroll
    for (int i = 0; i < 8; ++i) { mrow[i] = -INFINITY; lrow[i] = 0.f; }

    const float scale = 0.08838834764831845f;  // 1/sqrt(128)
    const int   pvs   = (tc & 7) << 3;
    const int   pss   = ltr << 3;

    for (int kt = 0; kt < 32; ++kt) {
        float4 kreg[4], vr0[4], vr1[4];
        if (kt < 31) {
            const size_t base = (size_t)(kt + 1) * 64 * 128;
            #pragma unroll
            for (int i = 0; i < 4; ++i)
                kreg[i] = *(const float4*)(kb + base + (size_t)kk0 * 128 + sg * 16 + (i << 2));
            #pragma unroll
            for (int u = 0; u < 4; ++u) {
                vr0[u] = *(const float4*)(vb + base + (size_t)(2 * kp) * 128 + ds0 + (u << 2));
                vr1[u] = *(const float4*)(vb + base + (size_t)(2 * kp + 1) * 128 + ds0 + (u << 2));
            }
        }

        float sv[8][4];
        #pragma unroll
        for (int i = 0; i < 8; ++i)
            #pragma unroll
            for (int j = 0; j < 4; ++j) sv[i][j] = 0.f;

        #pragma unroll 4
        for (int d = 0; d < 64; ++d) {
            float4 a0 = *(const float4*)(&Qt[d][tr << 3]);
            float4 a1 = *(const float4*)(&Qt[d][(tr << 3) + 4]);
            float4 kv = *(const float4*)(&Kt[d][tc << 2]);
            const float av[8] = {a0.x, a0.y, a0.z, a0.w, a1.x, a1.y, a1.z, a1.w};
            const float bv[4] = {kv.x, kv.y, kv.z, kv.w};
            #pragma unroll
            for (int i = 0; i < 8; ++i)
                #pragma unroll
                for (int j = 0; j < 4; ++j)
                    sv[i][j] = fmaf(av[i], bv[j], sv[i][j]);
        }

        #pragma unroll
        for (int i = 0; i < 8; ++i) {
            #pragma unroll
            for (int j = 0; j < 4; ++j) sv[i][j] *= scale;
            float mx = fmaxf(fmaxf(sv[i][0], sv[i][1]), fmaxf(sv[i][2], sv[i][3]));
            mx = fmaxf(mx, __shfl_xor(mx, 1));
            mx = fmaxf(mx, __shfl_xor(mx, 2));
            mx = fmaxf(mx, __shfl_xor(mx, 4));
            mx = fmaxf(mx, __shfl_xor(mx, 8));
            if (mx > mrow[i]) {
                const float al = __expf(mrow[i] - mx);
                mrow[i] = mx;
                lrow[i] *= al;
                #pragma unroll
                for (int j = 0; j < 8; ++j) accO[i][j] *= al;
            }
            float ps = 0.f;
            #pragma unroll
            for (int j = 0; j < 4; ++j) {
                const float p = __expf(sv[i][j] - mrow[i]);
                sv[i][j] = p;
                ps += p;
            }
            ps += __shfl_xor(ps, 1);
            ps += __shfl_xor(ps, 2);
            ps += __shfl_xor(ps, 4);
            ps += __shfl_xor(ps, 8);
            lrow[i] += ps;
        }

        #pragma unroll
        for (int i = 0; i < 8; ++i) {
            half2v h0; h0[0] = (_Float16)sv[i][0]; h0[1] = (_Float16)sv[i][1];
            half2v h1; h1[0] = (_Float16)sv[i][2]; h1[1] = (_Float16)sv[i][3];
            uint2 wv;
            wv.x = __builtin_bit_cast(unsigned int, h0);
            wv.y = __builtin_bit_cast(unsigned int, h1);
            *reinterpret_cast<uint2*>(&Ps[wid][(ltr << 3) + i][(tc << 2) ^ pss]) = wv;
        }
        asm volatile("s_waitcnt lgkmcnt(0)" ::: "memory");

        for (int c = 0; c < 8; ++c) {
            uint4 vvu[8];
            #pragma unroll
            for (int e = 0; e < 8; ++e) {
                const int d = (e < 4) ? (tc << 2) + e : 64 + (tc << 2) + (e - 4);
                vvu[e] = *reinterpret_cast<const uint4*>(&Vt[d][(c << 3) ^ pvs]);
            }
            #pragma unroll
            for (int i = 0; i < 8; ++i) {
                uint4 ppu = *reinterpret_cast<const uint4*>(
                    &Ps[wid][(ltr << 3) + i][(c << 3) ^ pss]);
                const half2v* ph = reinterpret_cast<const half2v*>(&ppu);
                #pragma unroll
                for (int e = 0; e < 8; ++e) {
                    const half2v* vh = reinterpret_cast<const half2v*>(&vvu[e]);
                    float a = accO[i][e];
                    a = fdot2f(ph[0], vh[0], a);
                    a = fdot2f(ph[1], vh[1], a);
                    a = fdot2f(ph[2], vh[2], a);
                    a = fdot2f(ph[3], vh[3], a);
                    accO[i][e] = a;
                }
            }
        }

        if (kt < 31) {
            __syncthreads();
            #pragma unroll
            for (int i = 0; i < 4; ++i) {
                Kt[sg * 16 + (i << 2) + 0][kk0] = kreg[i].x;
                Kt[sg * 16 + (i << 2) + 1][kk0] = kreg[i].y;
                Kt[sg * 16 + (i << 2) + 2][kk0] = kreg[i].z;
                Kt[sg * 16 + (i << 2) + 3][kk0] = kreg[i].w;
            }
            #pragma unroll
            for (int u = 0; u < 4; ++u) {
                const float* p0 = (const float*)&vr0[u];
                const float* p1 = (const float*)&vr1[u];
                #pragma unroll
                for (int e = 0; e < 4; ++e) {
                    const int d = ds0 + (u << 2) + e;
                    const int off = (2 * kp) ^ (((d >> 2) & 7) << 3);
                    half2v h; h[0] = (_Float16)p0[e]; h[1] = (_Float16)p1[e];
                    *reinterpret_cast<half2v*>(&Vt[d][off]) = h;
                }
            }
            __syncthreads();
        }
    }

    const int b = bh >> 4, h = bh & 15;
    #pragma unroll
    for (int i = 0; i < 8; ++i) {
        const float inv = 1.f / lrow[i];
        const int srow = s0 + (tr << 3) + i;
        float* yp = y + ((size_t)(b * 2048 + srow)) * 2048 + h * 128;
        float4 o0, o1;
        o0.x = accO[i][0] * inv; o0.y = accO[i][1] * inv;
        o0.z = accO[i][2] * inv; o0.w = accO[i][3] * inv;
        o1.x = accO[i][4] * inv; o1.y = accO[i][5] * inv;
        o1.z = accO[i][6] * inv; o1.w = accO[i][7] * inv;
        *(float4*)(yp + (tc << 2))      = o0;
        *(float4*)(yp + 64 + (tc << 2)) = o1;
    }
}

extern "C" void kernel_launch(void* const* d_in, const int* in_sizes, int n_in,
                              void* d_out, int out_size, void* d_ws, size_t ws_size,
                              hipStream_t stream)
{
    const float* x  = (const float*)d_in[0];
    const float* Wc = (const float*)d_in[1];
    const float* bc = (const float*)d_in[2];
    const float* fq = (const float*)d_in[3];
    float* out = (float*)d_out;
    float* qws = (float*)d_ws;   // compact q, (B,H,S,64) fp32 = 16 MiB

    gemm_merged_kernel<<<1024, 256, 0, stream>>>(x, Wc, bc, fq, qws, out);
    attn_kernel<<<512, 256, 0, stream>>>(qws, out + K_OFF, out + V_OFF, out + Y_OFF);
}